// Round 11
// baseline (120.535 us; speedup 1.0000x reference)
//
#include <hip/hip_runtime.h>

#define B_   64
#define H_   128
#define W_   2048
#define HW_  (H_ * W_)        // 262144
#define OH_  128
#define OW_  2048

typedef float nfloat4 __attribute__((ext_vector_type(4)));

// OpenBLAS sgemm emulation — SkylakeX params (VERIFIED bit-exact in round 6):
//   SGEMM_DEFAULT_Q = 320; K = 262144 -> blocks 0..817 len 320,
//   blk 818: off 261760 len 192; blk 819: off 261952 len 192.
//   Per C element: single sequential FMA chain over k within each block;
//   cross-block C += S_blk ascending; + b_loc in fp32.
// !!! The per-(blk,b,j) fmaf sequence and the K2 fp32 replay are bit-locked —
// !!! optimizations may only change load mechanics / parallel mapping.
#define QBLK 320
#define NBLK 820

__device__ __forceinline__ int blk_off(int blk) {
    if (blk <= 818) return blk * QBLK;    // 818*320 = 261760
    return 261952;                        // blk 819
}
__device__ __forceinline__ int blk_len(int blk) {
    return (blk < 818) ? 320 : 192;
}

// ---------------------------------------------------------------------------
// K1: ONE CHAIN PER THREAD (round-10 lesson: wave count beats per-thread ILP).
// Block = one kblk, 384 threads = 6 waves; tid = j*64 + b.
// w transposed into LDS (wt[j][k], 7.7 KB) -> in-loop reads are wave-uniform
// (all 64 lanes same address = LDS broadcast, conflict-free).
// x streamed per-lane straight from global: lane b walks row b contiguously
// (float4 steps); the 6 j-waves re-read the same lines -> L1/L2 hits.
// Grid: 820 blocks x 6 waves = 4920 waves (~19/CU).
// Chain = exact k-ascending fmaf sequence of the verified round-6 kernel.
// part layout: [b*6+j][kblk]  (transposed for K1b coalescing).
// ---------------------------------------------------------------------------
#define WSTR 320
__global__ __launch_bounds__(384)
void st_block_sums(const float* __restrict__ x, const float* __restrict__ w,
                   float* __restrict__ part)
{
    __shared__ float wt[6 * WSTR];       // 7680 B
    const int kblk = blockIdx.x;
    const int tid  = threadIdx.x;

    const int off = blk_off(kblk);
    const int len = blk_len(kblk);       // 320 or 192
    const int nt4 = len >> 2;            // 80 or 48

    // stage w transposed: wt[j][k] = w[(off+k)*6 + j]; coalesced global read
    for (int e = tid; e < 6 * len; e += 384) {
        const float v = w[(size_t)off * 6 + e];
        const int k = e / 6, j = e % 6;
        wt[j * WSTR + k] = v;
    }
    __syncthreads();

    const int j = tid >> 6;              // 0..5
    const int b = tid & 63;

    const float* __restrict__ xp = x + (size_t)b * HW_ + off;
    const float* __restrict__ wr = wt + j * WSTR;

    float a = 0.f;
    for (int t4 = 0; t4 < nt4; ++t4) {
        const float4 xv = *(const float4*)(xp + t4 * 4);
        const float4 wv = *(const float4*)(wr + t4 * 4);   // wave-uniform
        a = fmaf(xv.x, wv.x, a);
        a = fmaf(xv.y, wv.y, a);
        a = fmaf(xv.z, wv.z, a);
        a = fmaf(xv.w, wv.w, a);
    }
    part[((size_t)b * 6 + j) * NBLK + kblk] = a;
}

// ---------------------------------------------------------------------------
// K1b: ordered cross-block accumulation (ascending), + b_loc in fp32.
// part[(b*6+j)][blk] contiguous per thread -> sequential streaming.
// ---------------------------------------------------------------------------
__global__ __launch_bounds__(64)
void st_theta_final(const float* __restrict__ part, const float* __restrict__ bl,
                    float* __restrict__ theta)
{
#pragma clang fp contract(off)
    const int i = blockIdx.x * 64 + threadIdx.x;   // 0..383
    const int j = i % 6;
    const float* __restrict__ p = part + (size_t)i * NBLK;
    float acc = p[0];                              // S_0 (beta=0)
    for (int blk = 1; blk < NBLK; ++blk)
        acc = acc + p[blk];
    theta[i] = acc + bl[j];
}

// window select: e[m] = v[s+m] for m=0..4, v = {A.xyzw, B.xyzw}, s in 0..3.
// Pure bit-moves (cndmask) — no FP arithmetic.
__device__ __forceinline__ void win5(const float4 A, const float4 Bv, const int s,
                                     float& e0, float& e1, float& e2,
                                     float& e3, float& e4)
{
    const bool s1 = (s & 1) != 0;
    const bool s2 = (s & 2) != 0;
    const float v0 = A.x, v1 = A.y, v2 = A.z, v3 = A.w;
    const float v4 = Bv.x, v5 = Bv.y, v6 = Bv.z, v7 = Bv.w;
    const float w0 = s1 ? v1 : v0;
    const float w1 = s1 ? v2 : v1;
    const float w2 = s1 ? v3 : v2;
    const float w3 = s1 ? v4 : v3;
    const float w4 = s1 ? v5 : v4;
    const float w5 = s1 ? v6 : v5;
    const float w6 = s1 ? v7 : v6;
    e0 = s2 ? w2 : w0;
    e1 = s2 ? w3 : w1;
    e2 = s2 ? w4 : w2;
    e3 = s2 ? w5 : w3;
    e4 = s2 ? w6 : w4;
}

// ---------------------------------------------------------------------------
// K2: bilinear sampler — faithful fp32 numpy replay downstream of theta
// (arithmetic IDENTICAL to round 6). Loads: fast path when the 4-px group is
// interior + consecutive (4 aligned float4 + window shifts, provably the same
// values); slow path = original 16 gathers otherwise.  (~19 us, near its
// 135 MB roofline; unchanged)
// ---------------------------------------------------------------------------
__global__ __launch_bounds__(256)
void st_sample(const float* __restrict__ x, const float* __restrict__ theta,
               float* __restrict__ out)
{
#pragma clang fp contract(off)
    __shared__ float th[6];
    const int blk = blockIdx.x;
    const int b   = blk >> 8;          // 256 blocks per batch
    const int rem = blk & 255;
    const int yo  = rem >> 1;
    const int seg = rem & 1;

    if (threadIdx.x < 6) th[threadIdx.x] = theta[b * 6 + threadIdx.x];
    __syncthreads();

    const float t00 = th[0], t01 = th[1], t02 = th[2];
    const float t10 = th[3], t11 = th[4], t12 = th[5];

    const int xo0 = seg * 1024 + threadIdx.x * 4;
    const float* __restrict__ img = x + (size_t)b * HW_;
    const float yof = (float)yo;

    const float cx1 = t01 * yof;
    const float cy1 = t11 * yof;

    float xq[4], yq[4];
    int x0c[4], x1c[4], y0c[4], y1c[4];
    int x0raw0 = 0;

#pragma unroll
    for (int i = 0; i < 4; ++i) {
        const float xof = (float)(xo0 + i);
        const float px  = t00 * xof;
        const float sx  = px + cx1;
        xq[i] = sx + t02;
        const float py  = t10 * xof;
        const float sy  = py + cy1;
        yq[i] = sy + t12;

        const int x0 = (int)floorf(xq[i]);
        const int y0 = (int)floorf(yq[i]);
        if (i == 0) x0raw0 = x0;
        x0c[i] = min(max(x0,     0), W_ - 1);
        x1c[i] = min(max(x0 + 1, 0), W_ - 1);
        y0c[i] = min(max(y0,     0), H_ - 1);
        y1c[i] = min(max(y0 + 1, 0), H_ - 1);
    }

    const bool fast =
        (x0raw0 >= 0) &&
        (x0c[1] == x0c[0] + 1) && (x0c[2] == x0c[0] + 2) && (x0c[3] == x0c[0] + 3) &&
        (x1c[3] == x0c[3] + 1) &&
        (y0c[1] == y0c[0]) && (y0c[2] == y0c[0]) && (y0c[3] == y0c[0]) &&
        (y1c[1] == y1c[0]) && (y1c[2] == y1c[0]) && (y1c[3] == y1c[0]);

    float Ia[4], Ib[4], Ic[4], Id[4];
    if (fast) {
        const int base = x0c[0];
        const int a0   = base & ~3;
        const int s    = base & 3;
        const float* r0 = img + y0c[0] * W_ + a0;
        const float* r1 = img + y1c[0] * W_ + a0;
        const float4 A  = *(const float4*)(r0);
        const float4 Bv = *(const float4*)(r0 + 4);
        const float4 C  = *(const float4*)(r1);
        const float4 D  = *(const float4*)(r1 + 4);
        float e0, e1, e2, e3, e4;
        win5(A, Bv, s, e0, e1, e2, e3, e4);
        Ia[0] = e0; Ia[1] = e1; Ia[2] = e2; Ia[3] = e3;
        Ic[0] = e1; Ic[1] = e2; Ic[2] = e3; Ic[3] = e4;
        win5(C, D, s, e0, e1, e2, e3, e4);
        Ib[0] = e0; Ib[1] = e1; Ib[2] = e2; Ib[3] = e3;
        Id[0] = e1; Id[1] = e2; Id[2] = e3; Id[3] = e4;
    } else {
#pragma unroll
        for (int i = 0; i < 4; ++i) {
            const float* r0 = img + y0c[i] * W_;
            const float* r1 = img + y1c[i] * W_;
            Ia[i] = r0[x0c[i]];
            Ib[i] = r1[x0c[i]];
            Ic[i] = r0[x1c[i]];
            Id[i] = r1[x1c[i]];
        }
    }

    nfloat4 o;
#pragma unroll
    for (int i = 0; i < 4; ++i) {
        const float x0f = (float)x0c[i], x1f = (float)x1c[i];
        const float y0f = (float)y0c[i], y1f = (float)y1c[i];

        const float gx = x1f - xq[i];
        const float fx = xq[i] - x0f;
        const float gy = y1f - yq[i];
        const float fy = yq[i] - y0f;

        const float wa = gx * gy;
        const float wb = gx * fy;
        const float wc = fx * gy;
        const float wd = fx * fy;

        const float pa = wa * Ia[i];
        const float pb = wb * Ib[i];
        const float s1 = pa + pb;
        const float pc = wc * Ic[i];
        const float s2 = s1 + pc;
        const float pd = wd * Id[i];
        o[i] = s2 + pd;
    }

    const size_t oidx = ((size_t)b * OH_ + yo) * OW_ + xo0;
    __builtin_nontemporal_store(o, (nfloat4*)(out + oidx));
}

extern "C" void kernel_launch(void* const* d_in, const int* in_sizes, int n_in,
                              void* d_out, int out_size, void* d_ws, size_t ws_size,
                              hipStream_t stream)
{
    const float* x  = (const float*)d_in[0];
    const float* w  = (const float*)d_in[1];
    const float* bl = (const float*)d_in[2];
    float* out = (float*)d_out;

    // d_out doubles as the 1.26 MB block-sum scratch (384*820 floats), fully
    // consumed by st_theta_final before st_sample overwrites every element.
    float* part  = (float*)d_out;
    float* theta = (float*)d_ws;    // 384 floats

    st_block_sums<<<NBLK, 384, 0, stream>>>(x, w, part);
    st_theta_final<<<6, 64, 0, stream>>>(part, bl, theta);
    st_sample<<<B_ * OH_ * 2, 256, 0, stream>>>(x, theta, out);
}

// Round 12
// 93.485 us; speedup vs baseline: 1.2893x; 1.2893x over previous
//
#include <hip/hip_runtime.h>

#define B_   64
#define H_   128
#define W_   2048
#define HW_  (H_ * W_)        // 262144
#define OH_  128
#define OW_  2048

typedef float nfloat4 __attribute__((ext_vector_type(4)));

// OpenBLAS sgemm emulation — SkylakeX params (VERIFIED bit-exact in round 6):
//   SGEMM_DEFAULT_Q = 320; K = 262144 -> blocks 0..817 len 320,
//   blk 818: off 261760 len 192; blk 819: off 261952 len 192.
//   Per C element: single sequential FMA chain over k within each block;
//   cross-block C += S_blk ascending; + b_loc in fp32.
// !!! The per-(blk,b,j) fmaf sequence and the K2 fp32 replay are bit-locked —
// !!! optimizations may only change load mechanics / parallel mapping.
#define QBLK 320
#define NBLK 820

__device__ __forceinline__ int blk_off(int blk) {
    if (blk <= 818) return blk * QBLK;    // 818*320 = 261760
    return 261952;                        // blk 819
}
__device__ __forceinline__ int blk_len(int blk) {
    return (blk < 818) ? 320 : 192;
}

// ---------------------------------------------------------------------------
// K1 (round-12): block = (kblk, 32-row half), 192 threads = 6 j x 32 b.
// Lessons applied: r10 = need many waves/block; r11 = lane-per-row global
// loads are VMEM-line-bound (64 lines/instr x6 redundant). Here:
//  - x staged ONCE, coalesced, with PRE-SWIZZLED global addresses
//    (unit u of row r fetched from u^(r&7); LDS written linearly; read side
//    applies the same XOR -> involution; spreads ds_read_b128 banks).
//  - w staged transposed wt[j][k] (r11-verified): chain reads are b128 with
//    only 2 distinct addresses per wave (broadcast).
//  - thread = one (j,b) chain: per t4 = 1 x-b128 + 1 w-b128 + 4 fmaf,
//    exact k-ascending fmaf sequence of the verified kernel.
// LDS = 40960 (x) + 7680 (w) = 48.6 KB -> 3 blocks/CU = 9 waves/CU.
// part layout: [b*6+j][kblk] (for K1b streaming).
// ---------------------------------------------------------------------------
__global__ __launch_bounds__(192)
void st_block_sums(const float* __restrict__ x, const float* __restrict__ w,
                   float* __restrict__ part)
{
    __shared__ float4 xs4[32 * 80];      // 40960 B, row stride 80 float4
    __shared__ float  wt[6 * QBLK];      //  7680 B
    const int kblk = blockIdx.x >> 1;
    const int half = blockIdx.x & 1;
    const int tid  = threadIdx.x;

    const int off = blk_off(kblk);
    const int len = blk_len(kblk);       // 320 or 192
    const int nt4 = len >> 2;            // 80 or 48 (both %8 == 0)
    const int b0  = half * 32;

    // stage x: row r, float4-unit slot f4 holds global unit f4^(r&7)
    // (swizzle stays inside aligned groups of 8 units = 128B; coalesced).
    for (int idx = tid; idx < 32 * 80; idx += 192) {
        const int r  = idx / 80;
        const int f4 = idx % 80;
        if (f4 < nt4) {
            const int ug = f4 ^ (r & 7);
            xs4[idx] = *(const float4*)(x + (size_t)(b0 + r) * HW_ + off + ug * 4);
        }
    }
    // stage w transposed: wt[j][k] = w[(off+k)*6 + j]; coalesced global read.
    for (int e = tid; e < 6 * len; e += 192) {
        const float v = w[(size_t)off * 6 + e];
        const int k = e / 6, j = e % 6;
        wt[j * QBLK + k] = v;
    }
    __syncthreads();

    const int j = tid >> 5;              // 0..5
    const int b = tid & 31;              // row within half
    const int swz = b & 7;

    const float4* __restrict__ xr = xs4 + b * 80;
    const float*  __restrict__ wr = wt + j * QBLK;

    float a = 0.f;
    for (int t4 = 0; t4 < nt4; ++t4) {
        const float4 xv = xr[t4 ^ swz];                    // global unit t4
        const float4 wv = *(const float4*)(wr + t4 * 4);   // w[k..k+3][j]
        a = fmaf(xv.x, wv.x, a);
        a = fmaf(xv.y, wv.y, a);
        a = fmaf(xv.z, wv.z, a);
        a = fmaf(xv.w, wv.w, a);
    }

    const int bg = b0 + b;
    part[((size_t)bg * 6 + j) * NBLK + kblk] = a;
}

// ---------------------------------------------------------------------------
// K1b: ordered cross-block accumulation (ascending), + b_loc in fp32.
// part[(b*6+j)][blk] contiguous per thread -> sequential streaming.
// ---------------------------------------------------------------------------
__global__ __launch_bounds__(64)
void st_theta_final(const float* __restrict__ part, const float* __restrict__ bl,
                    float* __restrict__ theta)
{
#pragma clang fp contract(off)
    const int i = blockIdx.x * 64 + threadIdx.x;   // 0..383
    const int j = i % 6;
    const float* __restrict__ p = part + (size_t)i * NBLK;
    float acc = p[0];                              // S_0 (beta=0)
    for (int blk = 1; blk < NBLK; ++blk)
        acc = acc + p[blk];
    theta[i] = acc + bl[j];
}

// window select: e[m] = v[s+m] for m=0..4, v = {A.xyzw, B.xyzw}, s in 0..3.
// Pure bit-moves (cndmask) — no FP arithmetic.
__device__ __forceinline__ void win5(const float4 A, const float4 Bv, const int s,
                                     float& e0, float& e1, float& e2,
                                     float& e3, float& e4)
{
    const bool s1 = (s & 1) != 0;
    const bool s2 = (s & 2) != 0;
    const float v0 = A.x, v1 = A.y, v2 = A.z, v3 = A.w;
    const float v4 = Bv.x, v5 = Bv.y, v6 = Bv.z, v7 = Bv.w;
    const float w0 = s1 ? v1 : v0;
    const float w1 = s1 ? v2 : v1;
    const float w2 = s1 ? v3 : v2;
    const float w3 = s1 ? v4 : v3;
    const float w4 = s1 ? v5 : v4;
    const float w5 = s1 ? v6 : v5;
    const float w6 = s1 ? v7 : v6;
    e0 = s2 ? w2 : w0;
    e1 = s2 ? w3 : w1;
    e2 = s2 ? w4 : w2;
    e3 = s2 ? w5 : w3;
    e4 = s2 ? w6 : w4;
}

// ---------------------------------------------------------------------------
// K2: bilinear sampler — faithful fp32 numpy replay downstream of theta
// (arithmetic IDENTICAL to round 6). Loads: fast path when the 4-px group is
// interior + consecutive (4 aligned float4 + window shifts, provably the same
// values); slow path = original 16 gathers otherwise. (~19-25 us, near the
// 135 MB / 6.3 TB/s = 21 us roofline; unchanged)
// ---------------------------------------------------------------------------
__global__ __launch_bounds__(256)
void st_sample(const float* __restrict__ x, const float* __restrict__ theta,
               float* __restrict__ out)
{
#pragma clang fp contract(off)
    __shared__ float th[6];
    const int blk = blockIdx.x;
    const int b   = blk >> 8;          // 256 blocks per batch
    const int rem = blk & 255;
    const int yo  = rem >> 1;
    const int seg = rem & 1;

    if (threadIdx.x < 6) th[threadIdx.x] = theta[b * 6 + threadIdx.x];
    __syncthreads();

    const float t00 = th[0], t01 = th[1], t02 = th[2];
    const float t10 = th[3], t11 = th[4], t12 = th[5];

    const int xo0 = seg * 1024 + threadIdx.x * 4;
    const float* __restrict__ img = x + (size_t)b * HW_;
    const float yof = (float)yo;

    const float cx1 = t01 * yof;
    const float cy1 = t11 * yof;

    float xq[4], yq[4];
    int x0c[4], x1c[4], y0c[4], y1c[4];
    int x0raw0 = 0;

#pragma unroll
    for (int i = 0; i < 4; ++i) {
        const float xof = (float)(xo0 + i);
        const float px  = t00 * xof;
        const float sx  = px + cx1;
        xq[i] = sx + t02;
        const float py  = t10 * xof;
        const float sy  = py + cy1;
        yq[i] = sy + t12;

        const int x0 = (int)floorf(xq[i]);
        const int y0 = (int)floorf(yq[i]);
        if (i == 0) x0raw0 = x0;
        x0c[i] = min(max(x0,     0), W_ - 1);
        x1c[i] = min(max(x0 + 1, 0), W_ - 1);
        y0c[i] = min(max(y0,     0), H_ - 1);
        y1c[i] = min(max(y0 + 1, 0), H_ - 1);
    }

    const bool fast =
        (x0raw0 >= 0) &&
        (x0c[1] == x0c[0] + 1) && (x0c[2] == x0c[0] + 2) && (x0c[3] == x0c[0] + 3) &&
        (x1c[3] == x0c[3] + 1) &&
        (y0c[1] == y0c[0]) && (y0c[2] == y0c[0]) && (y0c[3] == y0c[0]) &&
        (y1c[1] == y1c[0]) && (y1c[2] == y1c[0]) && (y1c[3] == y1c[0]);

    float Ia[4], Ib[4], Ic[4], Id[4];
    if (fast) {
        const int base = x0c[0];
        const int a0   = base & ~3;
        const int s    = base & 3;
        const float* r0 = img + y0c[0] * W_ + a0;
        const float* r1 = img + y1c[0] * W_ + a0;
        const float4 A  = *(const float4*)(r0);
        const float4 Bv = *(const float4*)(r0 + 4);
        const float4 C  = *(const float4*)(r1);
        const float4 D  = *(const float4*)(r1 + 4);
        float e0, e1, e2, e3, e4;
        win5(A, Bv, s, e0, e1, e2, e3, e4);
        Ia[0] = e0; Ia[1] = e1; Ia[2] = e2; Ia[3] = e3;
        Ic[0] = e1; Ic[1] = e2; Ic[2] = e3; Ic[3] = e4;
        win5(C, D, s, e0, e1, e2, e3, e4);
        Ib[0] = e0; Ib[1] = e1; Ib[2] = e2; Ib[3] = e3;
        Id[0] = e1; Id[1] = e2; Id[2] = e3; Id[3] = e4;
    } else {
#pragma unroll
        for (int i = 0; i < 4; ++i) {
            const float* r0 = img + y0c[i] * W_;
            const float* r1 = img + y1c[i] * W_;
            Ia[i] = r0[x0c[i]];
            Ib[i] = r1[x0c[i]];
            Ic[i] = r0[x1c[i]];
            Id[i] = r1[x1c[i]];
        }
    }

    nfloat4 o;
#pragma unroll
    for (int i = 0; i < 4; ++i) {
        const float x0f = (float)x0c[i], x1f = (float)x1c[i];
        const float y0f = (float)y0c[i], y1f = (float)y1c[i];

        const float gx = x1f - xq[i];
        const float fx = xq[i] - x0f;
        const float gy = y1f - yq[i];
        const float fy = yq[i] - y0f;

        const float wa = gx * gy;
        const float wb = gx * fy;
        const float wc = fx * gy;
        const float wd = fx * fy;

        const float pa = wa * Ia[i];
        const float pb = wb * Ib[i];
        const float s1 = pa + pb;
        const float pc = wc * Ic[i];
        const float s2 = s1 + pc;
        const float pd = wd * Id[i];
        o[i] = s2 + pd;
    }

    const size_t oidx = ((size_t)b * OH_ + yo) * OW_ + xo0;
    __builtin_nontemporal_store(o, (nfloat4*)(out + oidx));
}

extern "C" void kernel_launch(void* const* d_in, const int* in_sizes, int n_in,
                              void* d_out, int out_size, void* d_ws, size_t ws_size,
                              hipStream_t stream)
{
    const float* x  = (const float*)d_in[0];
    const float* w  = (const float*)d_in[1];
    const float* bl = (const float*)d_in[2];
    float* out = (float*)d_out;

    // d_out doubles as the 1.26 MB block-sum scratch (384*820 floats), fully
    // consumed by st_theta_final before st_sample overwrites every element.
    float* part  = (float*)d_out;
    float* theta = (float*)d_ws;    // 384 floats

    st_block_sums<<<NBLK * 2, 192, 0, stream>>>(x, w, part);
    st_theta_final<<<6, 64, 0, stream>>>(part, bl, theta);
    st_sample<<<B_ * OH_ * 2, 256, 0, stream>>>(x, theta, out);
}

// Round 13
// 86.100 us; speedup vs baseline: 1.3999x; 1.0858x over previous
//
#include <hip/hip_runtime.h>

#define B_   64
#define H_   128
#define W_   2048
#define HW_  (H_ * W_)        // 262144
#define OH_  128
#define OW_  2048

typedef float nfloat4 __attribute__((ext_vector_type(4)));

// OpenBLAS sgemm emulation — SkylakeX params (VERIFIED bit-exact in round 6):
//   SGEMM_DEFAULT_Q = 320; K = 262144 -> blocks 0..817 len 320,
//   blk 818: off 261760 len 192; blk 819: off 261952 len 192.
//   Per C element: single sequential FMA chain over k within each block;
//   cross-block C += S_blk ascending; + b_loc in fp32.
// !!! The per-(blk,b,j) fmaf sequence and the K2 fp32 replay are bit-locked —
// !!! optimizations may only change load mechanics / parallel mapping.
#define QBLK 320
#define NBLK 820

__device__ __forceinline__ int blk_off(int blk) {
    if (blk <= 818) return blk * QBLK;    // 818*320 = 261760
    return 261952;                        // blk 819
}
__device__ __forceinline__ int blk_len(int blk) {
    return (blk < 818) ? 320 : 192;
}

// ---------------------------------------------------------------------------
// K1 (round-13): r12 geometry (block = kblk x 32-row half, 192 thr = 6j x 32b)
// with the two measured fixes:
//  - x staging via global_load_lds width=16: pre-swizzled per-lane GLOBAL
//    address (unit f4 holds global unit f4^(r&7)), wave-uniform linear LDS
//    dest + lane*16 (T21 pattern). One vmcnt drain at the barrier — kills the
//    per-iter load->waitcnt->ds_write serialization (~10k cyc/block).
//  - w staging reg-batched (10 loads, then 10 transposed ds_writes).
//  - compute specialized for nt4 = 80 / 48 and fully unrolled -> compiler
//    prefetches ds_reads with counted lgkmcnt.
// part layout reverted to [kblk][b*6+j]: K1 store block-coalesced, K1b wave
// reads consecutive (r10's [b6j][kblk] layout cost ~20 us in K1b).
// ---------------------------------------------------------------------------
__global__ __launch_bounds__(192)
void st_block_sums(const float* __restrict__ x, const float* __restrict__ w,
                   float* __restrict__ part)
{
    __shared__ float4 xs4[32 * 80];      // 40960 B, row stride 80 float4
    __shared__ float  wt[6 * QBLK];      //  7680 B
    const int kblk = blockIdx.x >> 1;
    const int half = blockIdx.x & 1;
    const int tid  = threadIdx.x;

    const int off = blk_off(kblk);
    const int len = blk_len(kblk);       // 320 or 192
    const int nt4 = len >> 2;            // 80 or 48 (both %8 == 0)
    const int b0  = half * 32;

    const int widx = tid >> 6;           // wave 0..2
    const int lane = tid & 63;

    // x staging: slot idx holds global float4-unit (idx%80)^(r&7) of row r.
    // Wave-uniform guard on idx (base multiples of 64); f4-guard EXEC-masks
    // lanes (their slots are never read: 48 & 80 are multiples of 8).
#pragma unroll
    for (int i = 0; i < 14; ++i) {
        const int base = i * 192 + widx * 64;     // wave-uniform slot base
        const int idx  = base + lane;
        if (base < 32 * 80) {                     // uniform per wave
            const int r  = idx / 80;
            const int f4 = idx % 80;
            if (f4 < nt4) {
                const int ug = f4 ^ (r & 7);
                const float* gp = x + (size_t)(b0 + r) * HW_ + off + ug * 4;
                __builtin_amdgcn_global_load_lds(
                    (const __attribute__((address_space(1))) unsigned int*)gp,
                    (__attribute__((address_space(3))) unsigned int*)&xs4[base],
                    16, 0, 0);
            }
        }
    }

    // w staging: batched regs -> transposed LDS wt[j][k]
    float wreg[10];
#pragma unroll
    for (int i = 0; i < 10; ++i) {
        const int e = tid + i * 192;
        wreg[i] = (e < 6 * len) ? w[(size_t)off * 6 + e] : 0.f;
    }
#pragma unroll
    for (int i = 0; i < 10; ++i) {
        const int e = tid + i * 192;
        if (e < 6 * len) wt[(e % 6) * QBLK + (e / 6)] = wreg[i];
    }
    __syncthreads();   // drains global_load_lds (vmcnt) + ds_writes (lgkmcnt)

    const int j   = tid >> 5;            // 0..5
    const int b   = tid & 31;            // row within half
    const int swz = b & 7;

    const float4* __restrict__ xr = xs4 + b * 80;
    const float*  __restrict__ wr = wt + j * QBLK;

    float a = 0.f;
    if (nt4 == 80) {
#pragma unroll
        for (int t4 = 0; t4 < 80; ++t4) {
            const float4 xv = xr[t4 ^ swz];                    // global unit t4
            const float4 wv = *(const float4*)(wr + t4 * 4);   // w[k..k+3][j]
            a = fmaf(xv.x, wv.x, a);
            a = fmaf(xv.y, wv.y, a);
            a = fmaf(xv.z, wv.z, a);
            a = fmaf(xv.w, wv.w, a);
        }
    } else {
#pragma unroll
        for (int t4 = 0; t4 < 48; ++t4) {
            const float4 xv = xr[t4 ^ swz];
            const float4 wv = *(const float4*)(wr + t4 * 4);
            a = fmaf(xv.x, wv.x, a);
            a = fmaf(xv.y, wv.y, a);
            a = fmaf(xv.z, wv.z, a);
            a = fmaf(xv.w, wv.w, a);
        }
    }

    part[(size_t)kblk * 384 + (size_t)(b0 + b) * 6 + j] = a;
}

// ---------------------------------------------------------------------------
// K1b: ordered cross-block accumulation (ascending), + b_loc in fp32.
// part[kblk][i]: wave reads 64 consecutive dwords per iteration (coalesced).
// ---------------------------------------------------------------------------
__global__ __launch_bounds__(64)
void st_theta_final(const float* __restrict__ part, const float* __restrict__ bl,
                    float* __restrict__ theta)
{
#pragma clang fp contract(off)
    const int i = blockIdx.x * 64 + threadIdx.x;   // 0..383
    const int j = i % 6;
    float acc = part[i];                           // S_0 (beta=0)
    for (int blk = 1; blk < NBLK; ++blk)
        acc = acc + part[(size_t)blk * 384 + i];
    theta[i] = acc + bl[j];
}

// window select: e[m] = v[s+m] for m=0..4, v = {A.xyzw, B.xyzw}, s in 0..3.
// Pure bit-moves (cndmask) — no FP arithmetic.
__device__ __forceinline__ void win5(const float4 A, const float4 Bv, const int s,
                                     float& e0, float& e1, float& e2,
                                     float& e3, float& e4)
{
    const bool s1 = (s & 1) != 0;
    const bool s2 = (s & 2) != 0;
    const float v0 = A.x, v1 = A.y, v2 = A.z, v3 = A.w;
    const float v4 = Bv.x, v5 = Bv.y, v6 = Bv.z, v7 = Bv.w;
    const float w0 = s1 ? v1 : v0;
    const float w1 = s1 ? v2 : v1;
    const float w2 = s1 ? v3 : v2;
    const float w3 = s1 ? v4 : v3;
    const float w4 = s1 ? v5 : v4;
    const float w5 = s1 ? v6 : v5;
    const float w6 = s1 ? v7 : v6;
    e0 = s2 ? w2 : w0;
    e1 = s2 ? w3 : w1;
    e2 = s2 ? w4 : w2;
    e3 = s2 ? w5 : w3;
    e4 = s2 ? w6 : w4;
}

// ---------------------------------------------------------------------------
// K2: bilinear sampler — faithful fp32 numpy replay downstream of theta
// (arithmetic IDENTICAL to round 6). Fast path: interior + consecutive 4-px
// groups via 4 aligned float4 + window shifts; slow path = 16 gathers.
// (~20-25 us, near the 135 MB / 6.3 TB/s = 21 us roofline; unchanged)
// ---------------------------------------------------------------------------
__global__ __launch_bounds__(256)
void st_sample(const float* __restrict__ x, const float* __restrict__ theta,
               float* __restrict__ out)
{
#pragma clang fp contract(off)
    __shared__ float th[6];
    const int blk = blockIdx.x;
    const int b   = blk >> 8;          // 256 blocks per batch
    const int rem = blk & 255;
    const int yo  = rem >> 1;
    const int seg = rem & 1;

    if (threadIdx.x < 6) th[threadIdx.x] = theta[b * 6 + threadIdx.x];
    __syncthreads();

    const float t00 = th[0], t01 = th[1], t02 = th[2];
    const float t10 = th[3], t11 = th[4], t12 = th[5];

    const int xo0 = seg * 1024 + threadIdx.x * 4;
    const float* __restrict__ img = x + (size_t)b * HW_;
    const float yof = (float)yo;

    const float cx1 = t01 * yof;
    const float cy1 = t11 * yof;

    float xq[4], yq[4];
    int x0c[4], x1c[4], y0c[4], y1c[4];
    int x0raw0 = 0;

#pragma unroll
    for (int i = 0; i < 4; ++i) {
        const float xof = (float)(xo0 + i);
        const float px  = t00 * xof;
        const float sx  = px + cx1;
        xq[i] = sx + t02;
        const float py  = t10 * xof;
        const float sy  = py + cy1;
        yq[i] = sy + t12;

        const int x0 = (int)floorf(xq[i]);
        const int y0 = (int)floorf(yq[i]);
        if (i == 0) x0raw0 = x0;
        x0c[i] = min(max(x0,     0), W_ - 1);
        x1c[i] = min(max(x0 + 1, 0), W_ - 1);
        y0c[i] = min(max(y0,     0), H_ - 1);
        y1c[i] = min(max(y0 + 1, 0), H_ - 1);
    }

    const bool fast =
        (x0raw0 >= 0) &&
        (x0c[1] == x0c[0] + 1) && (x0c[2] == x0c[0] + 2) && (x0c[3] == x0c[0] + 3) &&
        (x1c[3] == x0c[3] + 1) &&
        (y0c[1] == y0c[0]) && (y0c[2] == y0c[0]) && (y0c[3] == y0c[0]) &&
        (y1c[1] == y1c[0]) && (y1c[2] == y1c[0]) && (y1c[3] == y1c[0]);

    float Ia[4], Ib[4], Ic[4], Id[4];
    if (fast) {
        const int base = x0c[0];
        const int a0   = base & ~3;
        const int s    = base & 3;
        const float* r0 = img + y0c[0] * W_ + a0;
        const float* r1 = img + y1c[0] * W_ + a0;
        const float4 A  = *(const float4*)(r0);
        const float4 Bv = *(const float4*)(r0 + 4);
        const float4 C  = *(const float4*)(r1);
        const float4 D  = *(const float4*)(r1 + 4);
        float e0, e1, e2, e3, e4;
        win5(A, Bv, s, e0, e1, e2, e3, e4);
        Ia[0] = e0; Ia[1] = e1; Ia[2] = e2; Ia[3] = e3;
        Ic[0] = e1; Ic[1] = e2; Ic[2] = e3; Ic[3] = e4;
        win5(C, D, s, e0, e1, e2, e3, e4);
        Ib[0] = e0; Ib[1] = e1; Ib[2] = e2; Ib[3] = e3;
        Id[0] = e1; Id[1] = e2; Id[2] = e3; Id[3] = e4;
    } else {
#pragma unroll
        for (int i = 0; i < 4; ++i) {
            const float* r0 = img + y0c[i] * W_;
            const float* r1 = img + y1c[i] * W_;
            Ia[i] = r0[x0c[i]];
            Ib[i] = r1[x0c[i]];
            Ic[i] = r0[x1c[i]];
            Id[i] = r1[x1c[i]];
        }
    }

    nfloat4 o;
#pragma unroll
    for (int i = 0; i < 4; ++i) {
        const float x0f = (float)x0c[i], x1f = (float)x1c[i];
        const float y0f = (float)y0c[i], y1f = (float)y1c[i];

        const float gx = x1f - xq[i];
        const float fx = xq[i] - x0f;
        const float gy = y1f - yq[i];
        const float fy = yq[i] - y0f;

        const float wa = gx * gy;
        const float wb = gx * fy;
        const float wc = fx * gy;
        const float wd = fx * fy;

        const float pa = wa * Ia[i];
        const float pb = wb * Ib[i];
        const float s1 = pa + pb;
        const float pc = wc * Ic[i];
        const float s2 = s1 + pc;
        const float pd = wd * Id[i];
        o[i] = s2 + pd;
    }

    const size_t oidx = ((size_t)b * OH_ + yo) * OW_ + xo0;
    __builtin_nontemporal_store(o, (nfloat4*)(out + oidx));
}

extern "C" void kernel_launch(void* const* d_in, const int* in_sizes, int n_in,
                              void* d_out, int out_size, void* d_ws, size_t ws_size,
                              hipStream_t stream)
{
    const float* x  = (const float*)d_in[0];
    const float* w  = (const float*)d_in[1];
    const float* bl = (const float*)d_in[2];
    float* out = (float*)d_out;

    // d_out doubles as the 1.26 MB block-sum scratch (820*384 floats), fully
    // consumed by st_theta_final before st_sample overwrites every element.
    float* part  = (float*)d_out;
    float* theta = (float*)d_ws;    // 384 floats

    st_block_sums<<<NBLK * 2, 192, 0, stream>>>(x, w, part);
    st_theta_final<<<6, 64, 0, stream>>>(part, bl, theta);
    st_sample<<<B_ * OH_ * 2, 256, 0, stream>>>(x, theta, out);
}